// Round 5
// baseline (321.580 us; speedup 1.0000x reference)
//
#include <hip/hip_runtime.h>
#include <hip/hip_bf16.h>
#include <math.h>

#define CCH 320
#define NHEADS 8
#define DH 40
#define HW 4096
#define FFI 1280

typedef __bf16 bf16x8 __attribute__((ext_vector_type(8)));
typedef unsigned short u16x8 __attribute__((ext_vector_type(8)));
typedef short s16x4 __attribute__((ext_vector_type(4)));
typedef float f32x4 __attribute__((ext_vector_type(4)));
typedef unsigned int u32x4 __attribute__((ext_vector_type(4)));

// Wt-region offsets (u16 elements)
#define WQ1BF_OFF 2539520
#define W2_OFF    2641920
#define WT_TOTAL  2949120

__device__ inline unsigned short f2bf(float f) {
    __hip_bfloat16 h = __float2bfloat16(f);
    return __builtin_bit_cast(unsigned short, h);
}
// HW packed f32x2 -> bf16x2 convert where available.
__device__ inline unsigned pk2bf(float a, float b) {
#if __has_builtin(__builtin_amdgcn_cvt_pk_bf16_f32)
    typedef __bf16 bf16x2 __attribute__((ext_vector_type(2)));
    bf16x2 r = __builtin_amdgcn_cvt_pk_bf16_f32(a, b);
    return __builtin_bit_cast(unsigned, r);
#else
    return (unsigned)f2bf(a) | ((unsigned)f2bf(b) << 16);
#endif
}
__device__ inline float bf2f(unsigned short u) {
    return __builtin_bit_cast(float, ((unsigned)u) << 16);
}
__device__ inline bf16x8 ldfrag(const unsigned short* p) {
    u16x8 raw = *reinterpret_cast<const u16x8*>(p);
    return __builtin_bit_cast(bf16x8, raw);
}
// Build a k=16 B-operand fragment from two packed bf16 dwords (no shuffle!).
__device__ inline s16x4 pk2frag(unsigned a, unsigned b) {
    unsigned long long v = (unsigned long long)a | ((unsigned long long)b << 32);
    return __builtin_bit_cast(s16x4, v);
}

// Bare HW exp2 — avoids the OCML non-DAZ fixup sequence on the softmax chain.
__device__ inline float ex2(float x) {
#if __has_builtin(__builtin_amdgcn_exp2f)
    return __builtin_amdgcn_exp2f(x);
#else
    return exp2f(x);
#endif
}
__device__ inline float fast_rcp(float x) {
#if __has_builtin(__builtin_amdgcn_rcpf)
    return __builtin_amdgcn_rcpf(x);
#else
    return 1.f / x;
#endif
}
// gelu(x) via Abramowitz–Stegun 7.1.26 erf (|err| <= 1.5e-7): ~14 VALU.
__device__ inline float fast_gelu(float x) {
    float z = fabsf(x) * 0.70710678118654752f;
    float t = fast_rcp(fmaf(0.3275911f, z, 1.f));
    float poly = fmaf(fmaf(fmaf(fmaf(1.061405429f, t, -1.453152027f), t,
                               1.421413741f), t, -0.284496736f), t,
                      0.254829592f) * t;
    float e = ex2(z * z * -1.4426950408889634f);
    float erfz = 1.f - poly * e;          // erf(|x|/sqrt2)
    float s = copysignf(erfz, x);
    return 0.5f * x * (1.f + s);
}

// Normalize 8 fp32 row elements with LN (mean, rstd, w, b) -> packed bf16x8.
__device__ inline u16x8 ln_pack(const float* ar, float mean, float rs,
                                const float* wp, const float* bp) {
    float4 x0 = *(const float4*)ar, x1 = *(const float4*)(ar + 4);
    float4 w0 = *(const float4*)wp, w1 = *(const float4*)(wp + 4);
    float4 b0 = *(const float4*)bp, b1 = *(const float4*)(bp + 4);
    unsigned r0 = pk2bf((x0.x - mean) * rs * w0.x + b0.x,
                        (x0.y - mean) * rs * w0.y + b0.y);
    unsigned r1 = pk2bf((x0.z - mean) * rs * w0.z + b0.z,
                        (x0.w - mean) * rs * w0.w + b0.w);
    unsigned r2 = pk2bf((x1.x - mean) * rs * w1.x + b1.x,
                        (x1.y - mean) * rs * w1.y + b1.y);
    unsigned r3 = pk2bf((x1.z - mean) * rs * w1.z + b1.z,
                        (x1.w - mean) * rs * w1.w + b1.w);
    u32x4 u = {r0, r1, r2, r3};
    return __builtin_bit_cast(u16x8, u);
}

// ---------------------------------------------------------------------------
// megaprep: weight transposes (620) + wq1 bf16 copy (25) + wq1^T (25) +
// pack_ctx (384) + gn_stats (256) + LN-stats zero (24). Grid 1334.
__global__ __launch_bounds__(256) void megaprep(
    const float* __restrict__ w_in, const float* __restrict__ wq1,
    const float* __restrict__ wk1, const float* __restrict__ wv1,
    const float* __restrict__ wo1, const float* __restrict__ wq2,
    const float* __restrict__ wo2, const float* __restrict__ w_out,
    const float* __restrict__ wff1, const float* __restrict__ wff2,
    const float* __restrict__ wk2, const float* __restrict__ wv2,
    unsigned short* __restrict__ Wt,
    const float* __restrict__ ctx, unsigned short* __restrict__ ctx_bf,
    const float* __restrict__ X, float2* __restrict__ gnp,
    float* __restrict__ lnst) {
    __shared__ float tile[64][65];
    __shared__ float s1[256], s2[256];
    const int b = blockIdx.x, tid = threadIdx.x;
    if (b >= 1310) {  // zero LN stats: 3*4096*2 floats = 6144 float4
        int idx = (b - 1310) * 256 + tid;
        *(float4*)(lnst + (size_t)idx * 4) = make_float4(0.f, 0.f, 0.f, 0.f);
        return;
    }
    if (b >= 670) {
        if (b < 1054) {  // pack_ctx: 77x768 fp32 -> 128x768 bf16, pad rows 0
            int idx = (b - 670) * 256 + tid;
            int row = idx / 768, col = idx - row * 768;
            float v = (row < 77) ? ctx[row * 768 + col] : 0.f;
            ctx_bf[idx] = f2bf(v);
        } else {  // gn_stats
            const int bg = b - 1054;
            const float* xg = X + bg * 5120;
            float s = 0.f, sq = 0.f;
#pragma unroll
            for (int i = 0; i < 20; ++i) { float v = xg[tid + i * 256]; s += v; sq += v * v; }
            s1[tid] = s; s2[tid] = sq; __syncthreads();
            for (int off = 128; off > 0; off >>= 1) {
                if (tid < off) { s1[tid] += s1[tid + off]; s2[tid] += s2[tid + off]; }
                __syncthreads();
            }
            if (tid == 0) gnp[bg] = make_float2(s1[0], s2[0]);
        }
        return;
    }
    if (b >= 620 && b < 645) {  // wq1 plain bf16 copy -> Wt[WQ1BF]
        int t = b - 620;
        int base = (t / 5) * 64 * 320 + (t % 5) * 64;
#pragma unroll
        for (int i = 0; i < 16; ++i) {
            int idx = tid + i * 256;
            int r = idx >> 6, cn = idx & 63;
            Wt[WQ1BF_OFF + base + r * 320 + cn] = f2bf(wq1[base + r * 320 + cn]);
        }
        return;
    }
    const float* src;
    int K, stride, dstoff, k0, n0;
    bool glu = false;
    if (b < 200) {
        int m = b / 25, t = b % 25;
        k0 = (t / 5) * 64; n0 = (t % 5) * 64;
        K = 320; stride = 320; dstoff = m * 102400;
        src = (m == 0) ? w_in : (m == 1) ? wq1 : (m == 2) ? wk1 :
              (m == 3) ? wv1 : (m == 4) ? wo1 : (m == 5) ? wq2 :
              (m == 6) ? wo2 : w_out;
    } else if (b < 300) {
        int t = b - 200;
        k0 = (t / 5) * 64; n0 = (t % 5) * 64;
        K = 1280; stride = 320; dstoff = 1638400; src = wff2;
    } else if (b < 500) {
        int t = b - 300;
        k0 = (t / 40) * 64; n0 = (t % 40) * 64;
        K = 320; stride = 2560; dstoff = 819200; src = wff1; glu = true;
    } else if (b < 560) {
        int t = b - 500;
        k0 = (t / 5) * 64; n0 = (t % 5) * 64;
        K = 768; stride = 320; dstoff = 2048000; src = wk2;
    } else if (b < 620) {
        int t = b - 560;
        k0 = (t / 5) * 64; n0 = (t % 5) * 64;
        K = 768; stride = 320; dstoff = 2048000 + 245760; src = wv2;
    } else {  // [645,670): wq1^T into W2 rows 0..319 (Bt layout for fused QKV)
        int t = b - 645;
        k0 = (t / 5) * 64; n0 = (t % 5) * 64;
        K = 320; stride = 320; dstoff = W2_OFF; src = wq1;
    }
#pragma unroll
    for (int i = 0; i < 16; ++i) {
        int idx = tid + i * 256;
        int r = idx >> 6, cn = idx & 63;
        int scol = glu ? ((n0 >> 1) + (cn >> 1) + (cn & 1) * FFI) : (n0 + cn);
        tile[r][cn] = src[(size_t)(k0 + r) * stride + scol];
    }
    __syncthreads();
#pragma unroll
    for (int i = 0; i < 16; ++i) {
        int idx = tid + i * 256;
        int cl = idx >> 6, cr = idx & 63;
        Wt[dstoff + (size_t)(n0 + cl) * K + k0 + cr] = f2bf(tile[cr][cl]);
    }
}

// ---------------------------------------------------------------------------
__global__ __launch_bounds__(256) void gn_apply(const float* __restrict__ X,
                                                const float2* __restrict__ part,
                                                const float* __restrict__ w,
                                                const float* __restrict__ b,
                                                unsigned short* __restrict__ Y) {
    __shared__ float tile[64][65];
    __shared__ float gm[32], gr[32];
    const int tid = threadIdx.x;
    const int hw0 = blockIdx.x * 64, c0 = blockIdx.y * 64;
    if (tid < 32) {
        float s = 0.f, sq = 0.f;
#pragma unroll
        for (int i = 0; i < 8; ++i) { float2 p = part[tid * 8 + i]; s += p.x; sq += p.y; }
        float mean = s * (1.f / 40960.f);
        float var  = sq * (1.f / 40960.f) - mean * mean;
        gm[tid] = mean; gr[tid] = rsqrtf(var + 1e-6f);
    }
#pragma unroll
    for (int i = 0; i < 16; ++i) {
        int idx = tid + i * 256;
        int r = idx >> 6, col = idx & 63;
        tile[r][col] = X[(size_t)(c0 + r) * HW + hw0 + col];
    }
    __syncthreads();
#pragma unroll
    for (int i = 0; i < 16; ++i) {
        int idx = tid + i * 256;
        int hwl = idx >> 6, cl = idx & 63;
        int c = c0 + cl, g = c / 10;
        float v = (tile[cl][hwl] - gm[g]) * gr[g] * w[c] + b[c];
        Y[(size_t)(hw0 + hwl) * CCH + c] = f2bf(v);
    }
}

// ---------------------------------------------------------------------------
// gemm4 (proven double-buffer GEMM).
// Modes: 0 fp32+bias(+res)(+row-stats atomics) | 2 QK-pack*scale (+pad-zero) |
//        4 bf16+bias+res | 5 GLU-interleaved | 8 ctx kv-merged (+pads) |
//        9 transposed fp32 out + x | 10 transposed bf16 store (weight fusion) |
//        11 fused QKV: Qp*scale | Kp | Vt (+pads/ones)
// LNA=true: A-operand is fp32 t_ normalized on-the-fly with (lnstats, lnw,
// lnb) during LDS staging — replaces the standalone ln_kernel dispatches.
template <int MT, int K, bool LNA = false>
__global__ __launch_bounds__(256) void gemm4(
    const unsigned short* __restrict__ A,
    const float* __restrict__ Af,
    const float* __restrict__ lnw,
    const float* __restrict__ lnb,
    const float* __restrict__ lnstats,
    float* __restrict__ ostats,
    const unsigned short* __restrict__ Bt,
    const float* __restrict__ bias,
    const float* __restrict__ res,
    void* __restrict__ Cout, void* __restrict__ Cout2,
    int N, int mode, float scale) {
    constexpr int NCH = K / 64;
    __shared__ __align__(16) unsigned short Ab[2][MT * 16 * 64];
    __shared__ __align__(16) unsigned short Bb[2][64 * 64];
    const int tid  = threadIdx.x;
    const int wave = tid >> 6, lane = tid & 63;
    const int quad = lane >> 4, c = lane & 15;
    const int m0 = blockIdx.y * (MT * 16);
    const int bn = blockIdx.x;

    f32x4 acc[MT];
#pragma unroll
    for (int i = 0; i < MT; ++i) acc[i] = (f32x4){0.f, 0.f, 0.f, 0.f};

    const unsigned short* aslab = LNA ? nullptr : A + (size_t)m0 * K;
    const float* afslab = LNA ? Af + (size_t)m0 * K : nullptr;
    const unsigned short* bslab = Bt + (size_t)(bn * 64) * K;

    constexpr int ITA = MT * 16 * 8 / 256;
    int arow[ITA], aoff[ITA];
#pragma unroll
    for (int i = 0; i < ITA; ++i) {
        int idx = tid + i * 256;
        arow[i] = idx >> 3;
        int g = idx & 7;
        aoff[i] = arow[i] * 64 + ((g ^ (arow[i] & 7)) * 8);
    }
    int brow[2], boff[2];
#pragma unroll
    for (int i = 0; i < 2; ++i) {
        int idx = tid + i * 256;
        brow[i] = idx >> 3;
        int g = idx & 7;
        boff[i] = brow[i] * 64 + ((g ^ (brow[i] & 7)) * 8);
    }
    const int ag = (tid & 7) * 8;

    float meanA[ITA], rsA[ITA];
    if constexpr (LNA) {
#pragma unroll
        for (int i = 0; i < ITA; ++i) {
            float2 st = *(const float2*)(lnstats + (size_t)(m0 + arow[i]) * 2);
            float mean = st.x * (1.f / 320.f);
            float var  = st.y * (1.f / 320.f) - mean * mean;
            meanA[i] = mean;
            rsA[i]   = rsqrtf(var + 1e-5f);
        }
    }

    {
        u16x8 ra[ITA], rb[2];
#pragma unroll
        for (int i = 0; i < ITA; ++i) {
            if constexpr (LNA)
                ra[i] = ln_pack(afslab + (size_t)arow[i] * K + ag, meanA[i], rsA[i],
                                lnw + ag, lnb + ag);
            else
                ra[i] = *(const u16x8*)(aslab + (size_t)arow[i] * K + ag);
        }
#pragma unroll
        for (int i = 0; i < 2; ++i)
            rb[i] = *(const u16x8*)(bslab + (size_t)brow[i] * K + ag);
#pragma unroll
        for (int i = 0; i < ITA; ++i) *(u16x8*)&Ab[0][aoff[i]] = ra[i];
#pragma unroll
        for (int i = 0; i < 2; ++i) *(u16x8*)&Bb[0][boff[i]] = rb[i];
    }
    __syncthreads();

    const int swz0 = (quad ^ (c & 7)) * 8;
    const int swz1 = ((quad + 4) ^ (c & 7)) * 8;
#pragma unroll
    for (int ch = 0; ch < NCH; ++ch) {
        const int buf = ch & 1;
        u16x8 ra[ITA], rb[2];
        if (ch + 1 < NCH) {
            const int kb = (ch + 1) * 64;
#pragma unroll
            for (int i = 0; i < ITA; ++i) {
                if constexpr (LNA)
                    ra[i] = ln_pack(afslab + (size_t)arow[i] * K + kb + ag,
                                    meanA[i], rsA[i], lnw + kb + ag, lnb + kb + ag);
                else
                    ra[i] = *(const u16x8*)(aslab + (size_t)arow[i] * K + kb + ag);
            }
#pragma unroll
            for (int i = 0; i < 2; ++i)
                rb[i] = *(const u16x8*)(bslab + (size_t)brow[i] * K + kb + ag);
        }
        bf16x8 b0 = ldfrag(&Bb[buf][(wave * 16 + c) * 64 + swz0]);
        bf16x8 b1 = ldfrag(&Bb[buf][(wave * 16 + c) * 64 + swz1]);
#pragma unroll
        for (int mt = 0; mt < MT; ++mt) {
            bf16x8 a0 = ldfrag(&Ab[buf][(mt * 16 + c) * 64 + swz0]);
            bf16x8 a1 = ldfrag(&Ab[buf][(mt * 16 + c) * 64 + swz1]);
            acc[mt] = __builtin_amdgcn_mfma_f32_16x16x32_bf16(a0, b0, acc[mt], 0, 0, 0);
            acc[mt] = __builtin_amdgcn_mfma_f32_16x16x32_bf16(a1, b1, acc[mt], 0, 0, 0);
        }
        if (ch + 1 < NCH) {
            const int nb = buf ^ 1;
#pragma unroll
            for (int i = 0; i < ITA; ++i) *(u16x8*)&Ab[nb][aoff[i]] = ra[i];
#pragma unroll
            for (int i = 0; i < 2; ++i) *(u16x8*)&Bb[nb][boff[i]] = rb[i];
        }
        __syncthreads();
    }

    const int col = bn * 64 + wave * 16 + c;
    float bval = 0.f;
    if (bias) bval = (mode == 5) ? bias[(col >> 1) + (col & 1) * FFI] : bias[col];

    if (mode == 9) {  // transposed fp32 out + x residual (final fused), float4
#pragma unroll
        for (int mt = 0; mt < MT; ++mt) {
            const int row0 = m0 + mt * 16 + quad * 4;
            float4 xv = *(const float4*)(res + (size_t)col * HW + row0);
            float4 ov;
            ov.x = acc[mt][0] + bval + xv.x;
            ov.y = acc[mt][1] + bval + xv.y;
            ov.z = acc[mt][2] + bval + xv.z;
            ov.w = acc[mt][3] + bval + xv.w;
            *(float4*)((float*)Cout + (size_t)col * HW + row0) = ov;
        }
        return;
    }
    float vv[MT][4];
#pragma unroll
    for (int mt = 0; mt < MT; ++mt) {
#pragma unroll
        for (int r = 0; r < 4; ++r) {
            const int row = m0 + mt * 16 + quad * 4 + r;
            float v = acc[mt][r];
            if (mode == 0) {
                v += bval;
                if (res) v += res[(size_t)row * N + col];
                ((float*)Cout)[(size_t)row * N + col] = v;
                vv[mt][r] = v;
            } else if (mode == 2) {
                int h = col & 7, d = col >> 3;
                ((unsigned short*)Cout)[(((size_t)h << 12) + row) * 64 + d] = f2bf(v * scale);
                if (d < 24)
                    ((unsigned short*)Cout)[(((size_t)h << 12) + row) * 64 + 40 + d] = 0;
            } else if (mode == 4) {
                ((unsigned short*)Cout)[(size_t)row * N + col] =
                    f2bf(v + bval + res[(size_t)row * N + col]);
            } else if (mode == 5) {
                v += bval;
                float other = __shfl_xor(v, 1, 64);
                if ((c & 1) == 0) {
                    float g = fast_gelu(other);
                    ((unsigned short*)Cout)[(size_t)row * FFI + (col >> 1)] = f2bf(v * g);
                }
            } else if (mode == 8) {  // ctx kv-merged, Lkp = 128
                if (col < 320) {
                    int h = col & 7, d = col >> 3;
                    ((unsigned short*)Cout)[(((size_t)h << 7) + row) * 64 + d] = f2bf(v);
                    if (d < 24)
                        ((unsigned short*)Cout)[(((size_t)h << 7) + row) * 64 + 40 + d] = 0;
                } else {
                    int c2 = col - 320;
                    int h = c2 & 7, d = c2 >> 3;
                    ((unsigned short*)Cout2)[(size_t)(h * 48 + d) * 128 + row] = f2bf(v);
                    if (d < 8)
                        ((unsigned short*)Cout2)[(size_t)(h * 48 + 40 + d) * 128 + row] =
                            (d == 0) ? (unsigned short)0x3F80 : (unsigned short)0;
                }
            } else if (mode == 10) {  // transposed bf16 store (Bt layout, K=320)
                ((unsigned short*)Cout)[(size_t)col * 320 + row] = f2bf(v);
            } else {  // 11: fused QKV -> Qp | Kp | Vt
                if (col < 320) {
                    int h = col & 7, d = col >> 3;
                    ((unsigned short*)Cout)[(((size_t)h << 12) + row) * 64 + d] = f2bf(v * scale);
                    if (d < 24)
                        ((unsigned short*)Cout)[(((size_t)h << 12) + row) * 64 + 40 + d] = 0;
                } else if (col < 640) {
                    int c2 = col - 320;
                    int h = c2 & 7, d = c2 >> 3;
                    ((unsigned short*)Cout2)[(((size_t)h << 12) + row) * 64 + d] = f2bf(v);
                    if (d < 24)
                        ((unsigned short*)Cout2)[(((size_t)h << 12) + row) * 64 + 40 + d] = 0;
                } else {
                    int c2 = col - 640;
                    int h = c2 & 7, d = c2 >> 3;
                    unsigned short* Vt_ = (unsigned short*)Cout2 + (size_t)8 * 4096 * 64;
                    Vt_[(((size_t)(h * 48 + d)) << 12) + row] = f2bf(v);
                    if (d < 8)
                        Vt_[(((size_t)(h * 48 + 40 + d)) << 12) + row] =
                            (d == 0) ? (unsigned short)0x3F80 : (unsigned short)0;
                }
            }
        }
    }
    // Row-stats epilogue for LN fusion: reduce over the 16-lane c-group, then
    // one atomicAdd pair per (row, col-group). ~20 adds/row total — trivial.
    if (mode == 0 && ostats) {
#pragma unroll
        for (int mt = 0; mt < MT; ++mt)
#pragma unroll
            for (int r = 0; r < 4; ++r) {
                float s = vv[mt][r], sq = s * s;
#pragma unroll
                for (int off = 1; off <= 8; off <<= 1) {
                    s  += __shfl_xor(s, off, 64);
                    sq += __shfl_xor(sq, off, 64);
                }
                if (c == 0) {
                    const int row = m0 + mt * 16 + quad * 4 + r;
                    atomicAdd(&ostats[(size_t)row * 2], s);
                    atomicAdd(&ostats[(size_t)row * 2 + 1], sq);
                }
            }
    }
}

// ---------------------------------------------------------------------------
// attn8: LDS-staged flash attention, 128 queries/block. Per-blk software
// pipeline: {4 QK MFMAs -> mask -> 8 exp2 -> pack -> 6 PV MFMAs} per blk;
// PV B-operand = packed exp2 dwords directly (identity layout).
template <int TILES, bool MASK, bool FINAL>
__global__ __launch_bounds__(256) void attn8(
    const unsigned short* __restrict__ Qp,
    const unsigned short* __restrict__ Kp,
    const unsigned short* __restrict__ Vt,
    float* __restrict__ pO, float* __restrict__ pL,
    unsigned short* __restrict__ Ofin,
    int Lk, int Lkp) {
    __shared__ __align__(16) unsigned short Kb[2][64 * 64];
    __shared__ __align__(16) unsigned short Vb[2][48 * 64];
    const int tid  = threadIdx.x;
    const int wave = tid >> 6, lane = tid & 63;
    const int quad = lane >> 4, c = lane & 15;
    const int id  = blockIdx.x;
    const int h   = id & 7;
    const int qt  = (id >> 3) & 31;
    const int seg = id >> 8;
    const int q0  = qt * 128 + wave * 32;

    const unsigned short* qbaseA = Qp + ((((size_t)h << 12) + q0 + c) << 6) + quad * 8;
    const bf16x8 bQA0 = ldfrag(qbaseA);
    const bf16x8 bQA1 = ldfrag(qbaseA + 32);
    const bf16x8 bQB0 = ldfrag(qbaseA + 1024);
    const bf16x8 bQB1 = ldfrag(qbaseA + 1024 + 32);

    f32x4 oA[3], oB[3];
#pragma unroll
    for (int i = 0; i < 3; ++i) {
        oA[i] = (f32x4){0.f, 0.f, 0.f, 0.f};
        oB[i] = (f32x4){0.f, 0.f, 0.f, 0.f};
    }

    const int kt0 = seg * TILES;
    const unsigned short* kglob = Kp + (((size_t)h * Lkp + kt0 * 64) << 6);
    const unsigned short* vglob = Vt + ((size_t)h * 48) * Lkp + kt0 * 64;

    const int r0 = lane >> 3;
    const int g  = lane & 7;
    int ldsoff[4];
    const unsigned short* gptr0[4];
#pragma unroll
    for (int i = 0; i < 4; ++i) {
        int s = wave + 4 * i;
        if (s < 8) {
            int row = s * 8 + r0;
            ldsoff[i] = row * 64 + (g ^ (row & 7)) * 8;
            gptr0[i]  = kglob + (size_t)row * 64 + g * 8;
        } else if (s < 14) {
            int d = (s - 8) * 8 + r0;
            ldsoff[i] = d * 64 + (g ^ (d & 7)) * 8;
            gptr0[i]  = vglob + (size_t)d * Lkp + g * 8;
        } else {
            ldsoff[i] = 0; gptr0[i] = nullptr;
        }
    }
    const bool isK[4] = {(wave + 0) < 8, (wave + 4) < 8, (wave + 8) < 8, (wave + 12) < 8};
    const bool act[4] = {true, true, true, (wave + 12) < 14};

    {
        u16x8 st[4];
#pragma unroll
        for (int i = 0; i < 4; ++i)
            if (act[i]) st[i] = *(const u16x8*)(gptr0[i]);
#pragma unroll
        for (int i = 0; i < 4; ++i)
            if (act[i]) {
                unsigned short* lp = isK[i] ? &Kb[0][ldsoff[i]] : &Vb[0][ldsoff[i]];
                *(u16x8*)lp = st[i];
            }
    }
    __syncthreads();

#pragma unroll
    for (int t = 0; t < TILES; ++t) {
        const int b = t & 1;
        u16x8 st[4];
        if (t + 1 < TILES) {
            const int kb = (t + 1) * 64;
#pragma unroll
            for (int i = 0; i < 4; ++i)
                if (act[i]) {
                    const unsigned short* gp =
                        isK[i] ? (gptr0[i] + (size_t)kb * 64) : (gptr0[i] + kb);
                    st[i] = *(const u16x8*)gp;
                }
        }
        const unsigned short* Kl = &Kb[b][0];
        const unsigned short* Vl = &Vb[b][0];
        const int sw0 = (quad ^ (c & 7)) * 8;
        const int sw1 = ((quad + 4) ^ (c & 7)) * 8;
        const int abs_kb = kt0 * 64 + t * 64;
        // ---- per-blk pipeline: QK -> mask -> exp2 -> pack -> PV ----
#pragma unroll
        for (int blk = 0; blk < 4; ++blk) {
            const int row = (blk * 16 + c) * 64;
            bf16x8 k0 = ldfrag(Kl + row + sw0);
            bf16x8 k1 = ldfrag(Kl + row + sw1);
            f32x4 zA = {0.f, 0.f, 0.f, 0.f};
            zA = __builtin_amdgcn_mfma_f32_16x16x32_bf16(k0, bQA0, zA, 0, 0, 0);
            zA = __builtin_amdgcn_mfma_f32_16x16x32_bf16(k1, bQA1, zA, 0, 0, 0);
            f32x4 zB = {0.f, 0.f, 0.f, 0.f};
            zB = __builtin_amdgcn_mfma_f32_16x16x32_bf16(k0, bQB0, zB, 0, 0, 0);
            zB = __builtin_amdgcn_mfma_f32_16x16x32_bf16(k1, bQB1, zB, 0, 0, 0);
            if (MASK) {
#pragma unroll
                for (int r = 0; r < 4; ++r) {
                    bool inv = (abs_kb + blk * 16 + quad * 4 + r >= Lk);
                    zA[r] = inv ? -30000.f : zA[r];
                    zB[r] = inv ? -30000.f : zB[r];
                }
            }
            s16x4 PA = pk2frag(pk2bf(ex2(zA[0]), ex2(zA[1])),
                               pk2bf(ex2(zA[2]), ex2(zA[3])));
            s16x4 PB = pk2frag(pk2bf(ex2(zB[0]), ex2(zB[1])),
                               pk2bf(ex2(zB[2]), ex2(zB[3])));
#pragma unroll
            for (int db = 0; db < 3; ++db) {
                const int dim = db * 16 + c;
                const int off =
                    (((blk * 2 + (quad >> 1)) ^ (dim & 7)) * 8) + (quad & 1) * 4;
                s16x4 vf = *(const s16x4*)(Vl + dim * 64 + off);
                oA[db] = __builtin_amdgcn_mfma_f32_16x16x16bf16_1k(vf, PA, oA[db], 0, 0, 0);
                oB[db] = __builtin_amdgcn_mfma_f32_16x16x16bf16_1k(vf, PB, oB[db], 0, 0, 0);
            }
        }
        if (t + 1 < TILES) {
            const int nb = b ^ 1;
#pragma unroll
            for (int i = 0; i < 4; ++i)
                if (act[i]) {
                    unsigned short* lp = isK[i] ? &Kb[nb][ldsoff[i]] : &Vb[nb][ldsoff[i]];
                    *(u16x8*)lp = st[i];
                }
        }
        __syncthreads();
    }
    if (FINAL) {
        // Single-segment: finalize here. l for query (q0[+16]+c) lives in the
        // quad==2 lane (PV ones-row, dim 40 = oX[2][0]).
        float lA = __shfl(oA[2][0], 32 + c, 64);
        float lB = __shfl(oB[2][0], 32 + c, 64);
        float liA = fast_rcp(lA), liB = fast_rcp(lB);
        unsigned short* oaptr = Ofin + (size_t)(q0 + c) * CCH + h * DH;
        unsigned short* obptr = Ofin + (size_t)(q0 + 16 + c) * CCH + h * DH;
        *(uint2*)(oaptr + quad * 4) =
            make_uint2(pk2bf(oA[0][0] * liA, oA[0][1] * liA),
                       pk2bf(oA[0][2] * liA, oA[0][3] * liA));
        *(uint2*)(oaptr + 16 + quad * 4) =
            make_uint2(pk2bf(oA[1][0] * liA, oA[1][1] * liA),
                       pk2bf(oA[1][2] * liA, oA[1][3] * liA));
        if (quad < 2)
            *(uint2*)(oaptr + 32 + quad * 4) =
                make_uint2(pk2bf(oA[2][0] * liA, oA[2][1] * liA),
                           pk2bf(oA[2][2] * liA, oA[2][3] * liA));
        *(uint2*)(obptr + quad * 4) =
            make_uint2(pk2bf(oB[0][0] * liB, oB[0][1] * liB),
                       pk2bf(oB[0][2] * liB, oB[0][3] * liB));
        *(uint2*)(obptr + 16 + quad * 4) =
            make_uint2(pk2bf(oB[1][0] * liB, oB[1][1] * liB),
                       pk2bf(oB[1][2] * liB, oB[1][3] * liB));
        if (quad < 2)
            *(uint2*)(obptr + 32 + quad * 4) =
                make_uint2(pk2bf(oB[2][0] * liB, oB[2][1] * liB),
                           pk2bf(oB[2][2] * liB, oB[2][3] * liB));
        return;
    }
    // epilogue: dims 0..39 per query; l = PV row 40 = oX[2][0] at quad==2
    const size_t base = ((size_t)(seg * 8 + h)) << 12;
    float* obA = pO + (base + q0 + c) * 40;
    *(float4*)(obA + quad * 4)      = make_float4(oA[0][0], oA[0][1], oA[0][2], oA[0][3]);
    *(float4*)(obA + 16 + quad * 4) = make_float4(oA[1][0], oA[1][1], oA[1][2], oA[1][3]);
    if (quad < 2)
        *(float4*)(obA + 32 + quad * 4) = make_float4(oA[2][0], oA[2][1], oA[2][2], oA[2][3]);
    float* obB = pO + (base + q0 + 16 + c) * 40;
    *(float4*)(obB + quad * 4)      = make_float4(oB[0][0], oB[0][1], oB[0][2], oB[0][3]);
    *(float4*)(obB + 16 + quad * 4) = make_float4(oB[1][0], oB[1][1], oB[1][2], oB[1][3]);
    if (quad < 2)
        *(float4*)(obB + 32 + quad * 4) = make_float4(oB[2][0], oB[2][1], oB[2][2], oB[2][3]);
    if (quad == 2) {
        pL[base + q0 + c]      = oA[2][0];
        pL[base + q0 + 16 + c] = oB[2][0];
    }
}

// Combine partials (vectorized): float4 loads, packed bf16 stores.
__global__ __launch_bounds__(256) void attn_combine2(
    const float* __restrict__ pO, const float* __restrict__ pL,
    unsigned short* __restrict__ O, int S) {
    int idx = blockIdx.x * 256 + threadIdx.x;  // < 8*4096*10, grid 1280
    int h = idx / (HW * 10);
    int rem = idx - h * (HW * 10);
    int row = rem / 10, dg = rem - row * 10;
    float4 num = make_float4(0.f, 0.f, 0.f, 0.f);
    float den = 0.f;
    for (int s = 0; s < S; ++s) {
        size_t base = ((size_t)(s * 8 + h)) << 12;
        float4 p = *(const float4*)(pO + (base + row) * 40 + dg * 4);
        num.x += p.x; num.y += p.y; num.z += p.z; num.w += p.w;
        den += pL[base + row];
    }
    float inv = fast_rcp(den);
    unsigned short* ob = O + (size_t)row * CCH + h * DH + dg * 4;
    unsigned lo = pk2bf(num.x * inv, num.y * inv);
    unsigned hi = pk2bf(num.z * inv, num.w * inv);
    *(uint2*)ob = make_uint2(lo, hi);
}

// ---------------------------------------------------------------------------
extern "C" void kernel_launch(void* const* d_in, const int* in_sizes, int n_in,
                              void* d_out, int out_size, void* d_ws, size_t ws_size,
                              hipStream_t stream) {
    const float* x     = (const float*)d_in[0];
    const float* ctx   = (const float*)d_in[1];
    const float* gn_w  = (const float*)d_in[2];
    const float* gn_b  = (const float*)d_in[3];
    const float* w_in  = (const float*)d_in[4];
    const float* b_in  = (const float*)d_in[5];
    const float* ln1_w = (const float*)d_in[6];
    const float* ln1_b = (const float*)d_in[7];
    const float* wq1   = (const float*)d_in[8];
    const float* wk1   = (const float*)d_in[9];
    const float* wv1   = (const float*)d_in[10];
    const float* wo1   = (const float*)d_in[11];
    const float* bo1   = (const float*)d_in[12];
    const float* ln2_w = (const float*)d_in[13];
    const float* ln2_b = (const float*)d_in[14];
    const float* wq2   = (const float*)d_in[15];
    const float* wk2   = (const float*)d_in[16];
    const float* wv2   = (const float*)d_in[17];
    const float* wo2   = (const float*)d_in[18];
    const float* bo2   = (const float*)d_in[19];
    const float* ln3_w = (const float*)d_in[20];
    const float* ln3_b = (const float*)d_in[21];
    const float* wff1  = (const float*)d_in[22];
    const float* bff1  = (const float*)d_in[23];
    const float* wff2  = (const float*)d_in[24];
    const float* bff2  = (const float*)d_in[25];
    const float* w_out = (const float*)d_in[26];
    const float* b_out = (const float*)d_in[27];
    float* out = (float*)d_out;

    const int NT = HW * CCH;  // 1,310,720
    // 8 segments if the workspace allows, else 4.
    const size_t u16_cnt = (size_t)NT * 3 + (size_t)HW * FFI +
                           (size_t)8 * 4096 * 64 * 2 + (size_t)8 * 48 * 4096 +
                           8 * 128 * 64 + 8 * 48 * 128 + WT_TOTAL + 128 * 768;
    const size_t need8 = (size_t)4 * (NT + 8 * NT + 8 * 32768 + 512) +
                         102400 + 2 * u16_cnt + 4096;
    const int SEGS = (ws_size >= need8) ? 8 : 4;

    float* ws = (float*)d_ws;
    float* t_   = ws;
    float* pO   = t_ + NT;
    float* pL   = pO + (size_t)SEGS * NT;
    float2* gnp = (float2*)(pL + (size_t)SEGS * 8 * 4096);
    float* lnst = (float*)(gnp + 256);          // 3 x 4096 x 2 floats
    unsigned short* u = (unsigned short*)(lnst + 24576);
    unsigned short* a_bf = u;                  u += NT;
    unsigned short* o_bf = u;                  u += NT;
    unsigned short* t_bf = u;                  u += NT;
    unsigned short* g_bf = u;                  u += HW * FFI;
    unsigned short* Qp   = u;                  u += 8 * 4096 * 64;
    unsigned short* Kp   = u;                  u += 8 * 4096 * 64;
    unsigned short* Vt   = u;                  u += 8 * 48 * 4096;  // after Kp!
    unsigned short* Kc   = u;                  u += 8 * 128 * 64;
    unsigned short* Vc   = u;                  u += 8 * 48 * 128;
    unsigned short* Wt   = u;                  u += WT_TOTAL;
    unsigned short* ctx_bf = u;                u += 128 * 768;

    float* lnst0 = lnst;
    float* lnst1 = lnst + 8192;
    float* lnst2 = lnst + 16384;

    const unsigned short* w_inT  = Wt;
    const unsigned short* wo1T   = Wt + 409600;
    const unsigned short* wq2T   = Wt + 512000;
    const unsigned short* wo2T   = Wt + 614400;
    const unsigned short* w_outT = Wt + 716800;
    const unsigned short* wff1T  = Wt + 819200;
    const unsigned short* wff2T  = Wt + 1638400;
    const unsigned short* wk2T   = Wt + 2048000;  // wv2T contiguous (N=640)
    const unsigned short* wk1T   = Wt + 204800;   // wv1T contiguous (N=640)
    const unsigned short* Wq1bf  = Wt + WQ1BF_OFF;
    unsigned short*       W2     = Wt + W2_OFF;   // [wq1T | WqkT | WqvT] 960x320

    const float qscale = 0.15811388300841897f * 1.4426950408889634f;  // 40^-.5 * log2e

    // 0) mega-prep: transposes + wq1 copies + pack_ctx + gn_stats + stats zero
    megaprep<<<1334, 256, 0, stream>>>(w_in, wq1, wk1, wv1, wo1, wq2, wo2, w_out,
                                       wff1, wff2, wk2, wv2, Wt, ctx, ctx_bf,
                                       x, gnp, lnst);
    // 0b) fused K/V weights: [Wqk|Wqv]^T = (wq1 @ [wk1|wv1])^T -> W2 rows 320..959
    gemm4<2, 320><<<dim3(10, 10), 256, 0, stream>>>(
        Wq1bf, nullptr, nullptr, nullptr, nullptr, nullptr,
        wk1T, nullptr, nullptr, W2 + (size_t)320 * 320, nullptr, 640, 10, 1.f);
    // 1) GroupNorm apply -> a_bf (HW,C)
    gn_apply<<<dim3(64, 5), 256, 0, stream>>>(x, gnp, gn_w, gn_b, a_bf);
    // 2) proj_in: t = a @ w_in + b_in (fp32) + row stats for ln1
    gemm4<2, 320><<<dim3(5, 128), 256, 0, stream>>>(
        a_bf, nullptr, nullptr, nullptr, nullptr, lnst0,
        w_inT, b_in, nullptr, t_, nullptr, CCH, 0, 1.f);
    // 3+4) LN1-fused QKV: [q|k|v] = ln1(t_) @ W2^T -> Qp/Kp/Vt (pads+ones)
    gemm4<2, 320, true><<<dim3(15, 128), 256, 0, stream>>>(
        nullptr, t_, ln1_w, ln1_b, lnst0, nullptr,
        W2, nullptr, nullptr, Qp, Kp, 960, 11, qscale);
    // 5) self-attention: 128 queries/block, SEGS segments
    if (SEGS == 8)
        attn8<8, false, false><<<2048, 256, 0, stream>>>(Qp, Kp, Vt, pO, pL, nullptr, HW, HW);
    else
        attn8<16, false, false><<<1024, 256, 0, stream>>>(Qp, Kp, Vt, pO, pL, nullptr, HW, HW);
    attn_combine2<<<1280, 256, 0, stream>>>(pO, pL, o_bf, SEGS);
    // 6) t += o @ wo1 + bo1 (+ row stats for ln2)
    gemm4<2, 320><<<dim3(5, 128), 256, 0, stream>>>(
        o_bf, nullptr, nullptr, nullptr, nullptr, lnst1,
        wo1T, bo1, t_, t_, nullptr, CCH, 0, 1.f);
    // 7+8a) LN2-fused cross q -> Qp
    gemm4<2, 320, true><<<dim3(5, 128), 256, 0, stream>>>(
        nullptr, t_, ln2_w, ln2_b, lnst1, nullptr,
        wq2T, nullptr, nullptr, Qp, nullptr, CCH, 2, qscale);
    // 8b) ctx K/V via MFMA gemm (mode 8, pads+ones self-written)
    gemm4<2, 768><<<dim3(10, 4), 256, 0, stream>>>(
        ctx_bf, nullptr, nullptr, nullptr, nullptr, nullptr,
        wk2T, nullptr, nullptr, Kc, Vc, 640, 8, 1.f);
    // 9) cross-attention (Lk=77, masked, single-seg -> finalize in-kernel)
    attn8<2, true, true><<<256, 256, 0, stream>>>(Qp, Kc, Vc, nullptr, nullptr, o_bf, 77, 128);
    // 10) t += o @ wo2 + bo2 (+ row stats for ln3)
    gemm4<2, 320><<<dim3(5, 128), 256, 0, stream>>>(
        o_bf, nullptr, nullptr, nullptr, nullptr, lnst2,
        wo2T, bo2, t_, t_, nullptr, CCH, 0, 1.f);
    // 11+12+13) LN3-fused FF1 with GEGLU -> g_bf
    gemm4<2, 320, true><<<dim3(40, 128), 256, 0, stream>>>(
        nullptr, t_, ln3_w, ln3_b, lnst2, nullptr,
        wff1T, bff1, nullptr, g_bf, nullptr, 2 * FFI, 5, 1.f);
    // 14) t_bf = bf16(t + g @ wff2 + bff2)
    gemm4<2, 1280><<<dim3(5, 128), 256, 0, stream>>>(
        g_bf, nullptr, nullptr, nullptr, nullptr, nullptr,
        wff2T, bff2, t_, t_bf, nullptr, CCH, 4, 1.f);
    // 15+16) out = (t_bf @ w_out + b_out)^T + x  (final fused, mode 9)
    gemm4<2, 320><<<dim3(5, 128), 256, 0, stream>>>(
        t_bf, nullptr, nullptr, nullptr, nullptr, nullptr,
        w_outT, b_out, x, out, nullptr, CCH, 9, 1.f);
}

// Round 6
// 285.112 us; speedup vs baseline: 1.1279x; 1.1279x over previous
//
#include <hip/hip_runtime.h>
#include <hip/hip_bf16.h>
#include <math.h>

#define CCH 320
#define NHEADS 8
#define DH 40
#define HW 4096
#define FFI 1280

typedef __bf16 bf16x8 __attribute__((ext_vector_type(8)));
typedef unsigned short u16x8 __attribute__((ext_vector_type(8)));
typedef short s16x4 __attribute__((ext_vector_type(4)));
typedef float f32x4 __attribute__((ext_vector_type(4)));
typedef unsigned int u32x4 __attribute__((ext_vector_type(4)));

// Wt-region offsets (u16 elements)
#define WQ1BF_OFF 2539520
#define W2_OFF    2641920
#define WT_TOTAL  2949120

__device__ inline unsigned short f2bf(float f) {
    __hip_bfloat16 h = __float2bfloat16(f);
    return __builtin_bit_cast(unsigned short, h);
}
// HW packed f32x2 -> bf16x2 convert where available.
__device__ inline unsigned pk2bf(float a, float b) {
#if __has_builtin(__builtin_amdgcn_cvt_pk_bf16_f32)
    typedef __bf16 bf16x2 __attribute__((ext_vector_type(2)));
    bf16x2 r = __builtin_amdgcn_cvt_pk_bf16_f32(a, b);
    return __builtin_bit_cast(unsigned, r);
#else
    return (unsigned)f2bf(a) | ((unsigned)f2bf(b) << 16);
#endif
}
__device__ inline float bf2f(unsigned short u) {
    return __builtin_bit_cast(float, ((unsigned)u) << 16);
}
__device__ inline bf16x8 ldfrag(const unsigned short* p) {
    u16x8 raw = *reinterpret_cast<const u16x8*>(p);
    return __builtin_bit_cast(bf16x8, raw);
}
// Build a k=16 B-operand fragment from two packed bf16 dwords (no shuffle!).
__device__ inline s16x4 pk2frag(unsigned a, unsigned b) {
    unsigned long long v = (unsigned long long)a | ((unsigned long long)b << 32);
    return __builtin_bit_cast(s16x4, v);
}

// Bare HW exp2 — avoids the OCML non-DAZ fixup sequence on the softmax chain.
__device__ inline float ex2(float x) {
#if __has_builtin(__builtin_amdgcn_exp2f)
    return __builtin_amdgcn_exp2f(x);
#else
    return exp2f(x);
#endif
}
__device__ inline float fast_rcp(float x) {
#if __has_builtin(__builtin_amdgcn_rcpf)
    return __builtin_amdgcn_rcpf(x);
#else
    return 1.f / x;
#endif
}
// gelu(x) via Abramowitz–Stegun 7.1.26 erf (|err| <= 1.5e-7): ~14 VALU.
__device__ inline float fast_gelu(float x) {
    float z = fabsf(x) * 0.70710678118654752f;
    float t = fast_rcp(fmaf(0.3275911f, z, 1.f));
    float poly = fmaf(fmaf(fmaf(fmaf(1.061405429f, t, -1.453152027f), t,
                               1.421413741f), t, -0.284496736f), t,
                      0.254829592f) * t;
    float e = ex2(z * z * -1.4426950408889634f);
    float erfz = 1.f - poly * e;          // erf(|x|/sqrt2)
    float s = copysignf(erfz, x);
    return 0.5f * x * (1.f + s);
}

// ---------------------------------------------------------------------------
// megaprep: weight transposes (620) + wq1 bf16 copy (25) + wq1^T (25) +
// pack_ctx (384) + gn_stats (256). Grid 1310.
__global__ __launch_bounds__(256) void megaprep(
    const float* __restrict__ w_in, const float* __restrict__ wq1,
    const float* __restrict__ wk1, const float* __restrict__ wv1,
    const float* __restrict__ wo1, const float* __restrict__ wq2,
    const float* __restrict__ wo2, const float* __restrict__ w_out,
    const float* __restrict__ wff1, const float* __restrict__ wff2,
    const float* __restrict__ wk2, const float* __restrict__ wv2,
    unsigned short* __restrict__ Wt,
    const float* __restrict__ ctx, unsigned short* __restrict__ ctx_bf,
    const float* __restrict__ X, float2* __restrict__ gnp) {
    __shared__ float tile[64][65];
    __shared__ float s1[256], s2[256];
    const int b = blockIdx.x, tid = threadIdx.x;
    if (b >= 670) {
        if (b < 1054) {  // pack_ctx: 77x768 fp32 -> 128x768 bf16, pad rows 0
            int idx = (b - 670) * 256 + tid;
            int row = idx / 768, col = idx - row * 768;
            float v = (row < 77) ? ctx[row * 768 + col] : 0.f;
            ctx_bf[idx] = f2bf(v);
        } else {  // gn_stats
            const int bg = b - 1054;
            const float* xg = X + bg * 5120;
            float s = 0.f, sq = 0.f;
#pragma unroll
            for (int i = 0; i < 20; ++i) { float v = xg[tid + i * 256]; s += v; sq += v * v; }
            s1[tid] = s; s2[tid] = sq; __syncthreads();
            for (int off = 128; off > 0; off >>= 1) {
                if (tid < off) { s1[tid] += s1[tid + off]; s2[tid] += s2[tid + off]; }
                __syncthreads();
            }
            if (tid == 0) gnp[bg] = make_float2(s1[0], s2[0]);
        }
        return;
    }
    if (b >= 620 && b < 645) {  // wq1 plain bf16 copy -> Wt[WQ1BF]
        int t = b - 620;
        int base = (t / 5) * 64 * 320 + (t % 5) * 64;
#pragma unroll
        for (int i = 0; i < 16; ++i) {
            int idx = tid + i * 256;
            int r = idx >> 6, cn = idx & 63;
            Wt[WQ1BF_OFF + base + r * 320 + cn] = f2bf(wq1[base + r * 320 + cn]);
        }
        return;
    }
    const float* src;
    int K, stride, dstoff, k0, n0;
    bool glu = false;
    if (b < 200) {
        int m = b / 25, t = b % 25;
        k0 = (t / 5) * 64; n0 = (t % 5) * 64;
        K = 320; stride = 320; dstoff = m * 102400;
        src = (m == 0) ? w_in : (m == 1) ? wq1 : (m == 2) ? wk1 :
              (m == 3) ? wv1 : (m == 4) ? wo1 : (m == 5) ? wq2 :
              (m == 6) ? wo2 : w_out;
    } else if (b < 300) {
        int t = b - 200;
        k0 = (t / 5) * 64; n0 = (t % 5) * 64;
        K = 1280; stride = 320; dstoff = 1638400; src = wff2;
    } else if (b < 500) {
        int t = b - 300;
        k0 = (t / 40) * 64; n0 = (t % 40) * 64;
        K = 320; stride = 2560; dstoff = 819200; src = wff1; glu = true;
    } else if (b < 560) {
        int t = b - 500;
        k0 = (t / 5) * 64; n0 = (t % 5) * 64;
        K = 768; stride = 320; dstoff = 2048000; src = wk2;
    } else if (b < 620) {
        int t = b - 560;
        k0 = (t / 5) * 64; n0 = (t % 5) * 64;
        K = 768; stride = 320; dstoff = 2048000 + 245760; src = wv2;
    } else {  // [645,670): wq1^T into W2 rows 0..319 (Bt layout for fused QKV)
        int t = b - 645;
        k0 = (t / 5) * 64; n0 = (t % 5) * 64;
        K = 320; stride = 320; dstoff = W2_OFF; src = wq1;
    }
#pragma unroll
    for (int i = 0; i < 16; ++i) {
        int idx = tid + i * 256;
        int r = idx >> 6, cn = idx & 63;
        int scol = glu ? ((n0 >> 1) + (cn >> 1) + (cn & 1) * FFI) : (n0 + cn);
        tile[r][cn] = src[(size_t)(k0 + r) * stride + scol];
    }
    __syncthreads();
#pragma unroll
    for (int i = 0; i < 16; ++i) {
        int idx = tid + i * 256;
        int cl = idx >> 6, cr = idx & 63;
        Wt[dstoff + (size_t)(n0 + cl) * K + k0 + cr] = f2bf(tile[cr][cl]);
    }
}

// ---------------------------------------------------------------------------
// LN: float4 loads (row = 320 f32 = 64 lanes * 4 + 64 tail).
__global__ __launch_bounds__(256) void ln_kernel(const float* __restrict__ X,
                                                 const float* __restrict__ w,
                                                 const float* __restrict__ b,
                                                 unsigned short* __restrict__ Y) {
    const int row  = blockIdx.x * 4 + (threadIdx.x >> 6);
    const int lane = threadIdx.x & 63;
    const float* xr = X + row * CCH;
    const float4 a = *(const float4*)(xr + lane * 4);
    const float  e = xr[256 + lane];
    float v[5] = {a.x, a.y, a.z, a.w, e};
    float s = 0.f, sq = 0.f;
#pragma unroll
    for (int i = 0; i < 5; ++i) { s += v[i]; sq += v[i] * v[i]; }
#pragma unroll
    for (int off = 32; off > 0; off >>= 1) {
        s  += __shfl_xor(s, off, 64);
        sq += __shfl_xor(sq, off, 64);
    }
    const float mean = s * (1.f / 320.f);
    const float var  = sq * (1.f / 320.f) - mean * mean;
    const float rstd = rsqrtf(var + 1e-5f);
    unsigned short* yr = Y + row * CCH;
    const float4 w4 = *(const float4*)(w + lane * 4);
    const float4 b4 = *(const float4*)(b + lane * 4);
    float r0 = (v[0] - mean) * rstd * w4.x + b4.x;
    float r1 = (v[1] - mean) * rstd * w4.y + b4.y;
    float r2 = (v[2] - mean) * rstd * w4.z + b4.z;
    float r3 = (v[3] - mean) * rstd * w4.w + b4.w;
    *(uint2*)(yr + lane * 4) = make_uint2(pk2bf(r0, r1), pk2bf(r2, r3));
    int ct = 256 + lane;
    yr[ct] = f2bf((v[4] - mean) * rstd * w[ct] + b[ct]);
}

// ---------------------------------------------------------------------------
// gemm_core: the proven double-buffer GEMM body as a device function so it can
// be block-range-merged with other work. Semantics identical to the R4 gemm4.
// Modes: 0 fp32+bias(+res) | 2 QK-pack*scale (+pad-zero) | 4 bf16+bias+res |
//        5 GLU-interleaved | 8 ctx kv-merged (+pads) | 9 transposed fp32
//        out + x | 10 transposed bf16 store | 11 fused QKV Qp|Kp|Vt
template <int MT, int K>
__device__ __forceinline__ void gemm_core(
    const int m0, const int bn, const int tid,
    unsigned short* __restrict__ AbBuf,   // [2][MT*16*64] flattened
    unsigned short* __restrict__ BbBuf,   // [2][64*64] flattened
    const unsigned short* __restrict__ A,
    const unsigned short* __restrict__ Bt,
    const float* __restrict__ bias,
    const float* __restrict__ res,
    void* __restrict__ Cout, void* __restrict__ Cout2,
    int N, int mode, float scale) {
    constexpr int NCH = K / 64;
    constexpr int ASZ = MT * 16 * 64;
    constexpr int BSZ = 64 * 64;
    const int wave = tid >> 6, lane = tid & 63;
    const int quad = lane >> 4, c = lane & 15;

    f32x4 acc[MT];
#pragma unroll
    for (int i = 0; i < MT; ++i) acc[i] = (f32x4){0.f, 0.f, 0.f, 0.f};

    const unsigned short* aslab = A + (size_t)m0 * K;
    const unsigned short* bslab = Bt + (size_t)(bn * 64) * K;

    constexpr int ITA = MT * 16 * 8 / 256;
    int arow[ITA], aoff[ITA];
#pragma unroll
    for (int i = 0; i < ITA; ++i) {
        int idx = tid + i * 256;
        arow[i] = idx >> 3;
        int g = idx & 7;
        aoff[i] = arow[i] * 64 + ((g ^ (arow[i] & 7)) * 8);
    }
    int brow[2], boff[2];
#pragma unroll
    for (int i = 0; i < 2; ++i) {
        int idx = tid + i * 256;
        brow[i] = idx >> 3;
        int g = idx & 7;
        boff[i] = brow[i] * 64 + ((g ^ (brow[i] & 7)) * 8);
    }
    const int ag = (tid & 7) * 8;

    {
        u16x8 ra[ITA], rb[2];
#pragma unroll
        for (int i = 0; i < ITA; ++i)
            ra[i] = *(const u16x8*)(aslab + (size_t)arow[i] * K + ag);
#pragma unroll
        for (int i = 0; i < 2; ++i)
            rb[i] = *(const u16x8*)(bslab + (size_t)brow[i] * K + ag);
#pragma unroll
        for (int i = 0; i < ITA; ++i) *(u16x8*)&AbBuf[aoff[i]] = ra[i];
#pragma unroll
        for (int i = 0; i < 2; ++i) *(u16x8*)&BbBuf[boff[i]] = rb[i];
    }
    __syncthreads();

    const int swz0 = (quad ^ (c & 7)) * 8;
    const int swz1 = ((quad + 4) ^ (c & 7)) * 8;
#pragma unroll
    for (int ch = 0; ch < NCH; ++ch) {
        const int buf = ch & 1;
        u16x8 ra[ITA], rb[2];
        if (ch + 1 < NCH) {
            const int kb = (ch + 1) * 64;
#pragma unroll
            for (int i = 0; i < ITA; ++i)
                ra[i] = *(const u16x8*)(aslab + (size_t)arow[i] * K + kb + ag);
#pragma unroll
            for (int i = 0; i < 2; ++i)
                rb[i] = *(const u16x8*)(bslab + (size_t)brow[i] * K + kb + ag);
        }
        bf16x8 b0 = ldfrag(&BbBuf[buf * BSZ + (wave * 16 + c) * 64 + swz0]);
        bf16x8 b1 = ldfrag(&BbBuf[buf * BSZ + (wave * 16 + c) * 64 + swz1]);
#pragma unroll
        for (int mt = 0; mt < MT; ++mt) {
            bf16x8 a0 = ldfrag(&AbBuf[buf * ASZ + (mt * 16 + c) * 64 + swz0]);
            bf16x8 a1 = ldfrag(&AbBuf[buf * ASZ + (mt * 16 + c) * 64 + swz1]);
            acc[mt] = __builtin_amdgcn_mfma_f32_16x16x32_bf16(a0, b0, acc[mt], 0, 0, 0);
            acc[mt] = __builtin_amdgcn_mfma_f32_16x16x32_bf16(a1, b1, acc[mt], 0, 0, 0);
        }
        if (ch + 1 < NCH) {
            const int nb = buf ^ 1;
#pragma unroll
            for (int i = 0; i < ITA; ++i) *(u16x8*)&AbBuf[nb * ASZ + aoff[i]] = ra[i];
#pragma unroll
            for (int i = 0; i < 2; ++i) *(u16x8*)&BbBuf[nb * BSZ + boff[i]] = rb[i];
        }
        __syncthreads();
    }

    const int col = bn * 64 + wave * 16 + c;
    float bval = 0.f;
    if (bias) bval = (mode == 5) ? bias[(col >> 1) + (col & 1) * FFI] : bias[col];

    if (mode == 9) {  // transposed fp32 out + x residual (final fused), float4
#pragma unroll
        for (int mt = 0; mt < MT; ++mt) {
            const int row0 = m0 + mt * 16 + quad * 4;
            float4 xv = *(const float4*)(res + (size_t)col * HW + row0);
            float4 ov;
            ov.x = acc[mt][0] + bval + xv.x;
            ov.y = acc[mt][1] + bval + xv.y;
            ov.z = acc[mt][2] + bval + xv.z;
            ov.w = acc[mt][3] + bval + xv.w;
            *(float4*)((float*)Cout + (size_t)col * HW + row0) = ov;
        }
        return;
    }
#pragma unroll
    for (int mt = 0; mt < MT; ++mt) {
#pragma unroll
        for (int r = 0; r < 4; ++r) {
            const int row = m0 + mt * 16 + quad * 4 + r;
            float v = acc[mt][r];
            if (mode == 0) {
                v += bval;
                if (res) v += res[(size_t)row * N + col];
                ((float*)Cout)[(size_t)row * N + col] = v;
            } else if (mode == 2) {
                int h = col & 7, d = col >> 3;
                ((unsigned short*)Cout)[(((size_t)h << 12) + row) * 64 + d] = f2bf(v * scale);
                if (d < 24)
                    ((unsigned short*)Cout)[(((size_t)h << 12) + row) * 64 + 40 + d] = 0;
            } else if (mode == 4) {
                ((unsigned short*)Cout)[(size_t)row * N + col] =
                    f2bf(v + bval + res[(size_t)row * N + col]);
            } else if (mode == 5) {
                v += bval;
                float other = __shfl_xor(v, 1, 64);
                if ((c & 1) == 0) {
                    float g = fast_gelu(other);
                    ((unsigned short*)Cout)[(size_t)row * FFI + (col >> 1)] = f2bf(v * g);
                }
            } else if (mode == 8) {  // ctx kv-merged, Lkp = 128
                if (col < 320) {
                    int h = col & 7, d = col >> 3;
                    ((unsigned short*)Cout)[(((size_t)h << 7) + row) * 64 + d] = f2bf(v);
                    if (d < 24)
                        ((unsigned short*)Cout)[(((size_t)h << 7) + row) * 64 + 40 + d] = 0;
                } else {
                    int c2 = col - 320;
                    int h = c2 & 7, d = c2 >> 3;
                    ((unsigned short*)Cout2)[(size_t)(h * 48 + d) * 128 + row] = f2bf(v);
                    if (d < 8)
                        ((unsigned short*)Cout2)[(size_t)(h * 48 + 40 + d) * 128 + row] =
                            (d == 0) ? (unsigned short)0x3F80 : (unsigned short)0;
                }
            } else if (mode == 10) {  // transposed bf16 store (Bt layout, K=320)
                ((unsigned short*)Cout)[(size_t)col * 320 + row] = f2bf(v);
            } else {  // 11: fused QKV -> Qp | Kp | Vt
                if (col < 320) {
                    int h = col & 7, d = col >> 3;
                    ((unsigned short*)Cout)[(((size_t)h << 12) + row) * 64 + d] = f2bf(v * scale);
                    if (d < 24)
                        ((unsigned short*)Cout)[(((size_t)h << 12) + row) * 64 + 40 + d] = 0;
                } else if (col < 640) {
                    int c2 = col - 320;
                    int h = c2 & 7, d = c2 >> 3;
                    ((unsigned short*)Cout2)[(((size_t)h << 12) + row) * 64 + d] = f2bf(v);
                    if (d < 24)
                        ((unsigned short*)Cout2)[(((size_t)h << 12) + row) * 64 + 40 + d] = 0;
                } else {
                    int c2 = col - 640;
                    int h = c2 & 7, d = c2 >> 3;
                    unsigned short* Vt_ = (unsigned short*)Cout2 + (size_t)8 * 4096 * 64;
                    Vt_[(((size_t)(h * 48 + d)) << 12) + row] = f2bf(v);
                    if (d < 8)
                        Vt_[(((size_t)(h * 48 + 40 + d)) << 12) + row] =
                            (d == 0) ? (unsigned short)0x3F80 : (unsigned short)0;
                }
            }
        }
    }
}

// Thin wrapper kernel (same launch shapes as before).
template <int MT, int K>
__global__ __launch_bounds__(256) void gemm4(
    const unsigned short* __restrict__ A,
    const unsigned short* __restrict__ Bt,
    const float* __restrict__ bias,
    const float* __restrict__ res,
    void* __restrict__ Cout, void* __restrict__ Cout2,
    int N, int mode, float scale) {
    __shared__ __align__(16) unsigned short Ab[2 * MT * 16 * 64];
    __shared__ __align__(16) unsigned short Bb[2 * 64 * 64];
    gemm_core<MT, K>(blockIdx.y * (MT * 16), blockIdx.x, threadIdx.x,
                     Ab, Bb, A, Bt, bias, res, Cout, Cout2, N, mode, scale);
}

// ---------------------------------------------------------------------------
// prep2: weight-fusion GEMM (blocks 0..99, mode 10) + gn_apply (100..419).
// Both depend only on megaprep — merged to save one graph node.
struct SmemPrep2 {
    union {
        struct { unsigned short Ab[2 * 2 * 16 * 64]; unsigned short Bb[2 * 64 * 64]; } g;
        struct { float tile[64][65]; float gm[32]; float gr[32]; } n;
    };
};
__global__ __launch_bounds__(256) void prep2(
    const unsigned short* __restrict__ Wq1bf,
    const unsigned short* __restrict__ wk1T,
    unsigned short* __restrict__ W2kv,
    const float* __restrict__ X, const float2* __restrict__ part,
    const float* __restrict__ gw, const float* __restrict__ gb,
    unsigned short* __restrict__ Y) {
    __shared__ __align__(16) SmemPrep2 sm;
    const int b = blockIdx.x, tid = threadIdx.x;
    if (b < 100) {  // [Wqk|Wqv]^T = (wq1 @ [wk1|wv1])^T, grid was (10,10)
        gemm_core<2, 320>((b / 10) * 32, b % 10, tid, sm.g.Ab, sm.g.Bb,
                          Wq1bf, wk1T, nullptr, nullptr, W2kv, nullptr,
                          640, 10, 1.f);
        return;
    }
    // gn_apply body, grid was (64,5)
    const int bb = b - 100;
    const int hw0 = (bb & 63) * 64, c0 = (bb >> 6) * 64;
    if (tid < 32) {
        float s = 0.f, sq = 0.f;
#pragma unroll
        for (int i = 0; i < 8; ++i) { float2 p = part[tid * 8 + i]; s += p.x; sq += p.y; }
        float mean = s * (1.f / 40960.f);
        float var  = sq * (1.f / 40960.f) - mean * mean;
        sm.n.gm[tid] = mean; sm.n.gr[tid] = rsqrtf(var + 1e-6f);
    }
#pragma unroll
    for (int i = 0; i < 16; ++i) {
        int idx = tid + i * 256;
        int r = idx >> 6, col = idx & 63;
        sm.n.tile[r][col] = X[(size_t)(c0 + r) * HW + hw0 + col];
    }
    __syncthreads();
#pragma unroll
    for (int i = 0; i < 16; ++i) {
        int idx = tid + i * 256;
        int hwl = idx >> 6, cl = idx & 63;
        int c = c0 + cl, g = c / 10;
        float v = (sm.n.tile[cl][hwl] - sm.n.gm[g]) * sm.n.gr[g] * gw[c] + gb[c];
        Y[(size_t)(hw0 + hwl) * CCH + c] = f2bf(v);
    }
}

// ---------------------------------------------------------------------------
// cross_merged: cross-q mode-2 GEMM (blocks 0..639) + ctx K/V mode-8 GEMM
// (640..679). Both ready after the wo1 GEMM + megaprep — merged; the 40 small
// K=768 blocks backfill CUs the 640-block wave leaves idle.
__global__ __launch_bounds__(256) void cross_merged(
    const unsigned short* __restrict__ a_bf,
    const unsigned short* __restrict__ wq2T,
    unsigned short* __restrict__ Qp, float qscale,
    const unsigned short* __restrict__ ctx_bf,
    const unsigned short* __restrict__ wk2T,
    unsigned short* __restrict__ Kc, unsigned short* __restrict__ Vc) {
    __shared__ __align__(16) unsigned short Ab[2 * 2 * 16 * 64];
    __shared__ __align__(16) unsigned short Bb[2 * 64 * 64];
    const int b = blockIdx.x, tid = threadIdx.x;
    if (b < 640) {  // cross q: grid was (5,128), mode 2
        gemm_core<2, 320>((b / 5) * 32, b % 5, tid, Ab, Bb,
                          a_bf, wq2T, nullptr, nullptr, Qp, nullptr,
                          CCH, 2, qscale);
    } else {  // ctx K/V: grid was (10,4), mode 8
        const int bb = b - 640;
        gemm_core<2, 768>((bb / 10) * 32, bb % 10, tid, Ab, Bb,
                          ctx_bf, wk2T, nullptr, nullptr, Kc, Vc,
                          640, 8, 1.f);
    }
}

// ---------------------------------------------------------------------------
// attn8: LDS-staged flash attention, 128 queries/block. Per-blk software
// pipeline: {4 QK MFMAs -> mask -> 8 exp2 -> pack -> 6 PV MFMAs} per blk;
// PV B-operand = packed exp2 dwords directly (identity layout).
template <int TILES, bool MASK, bool FINAL>
__global__ __launch_bounds__(256) void attn8(
    const unsigned short* __restrict__ Qp,
    const unsigned short* __restrict__ Kp,
    const unsigned short* __restrict__ Vt,
    float* __restrict__ pO, float* __restrict__ pL,
    unsigned short* __restrict__ Ofin,
    int Lk, int Lkp) {
    __shared__ __align__(16) unsigned short Kb[2][64 * 64];
    __shared__ __align__(16) unsigned short Vb[2][48 * 64];
    const int tid  = threadIdx.x;
    const int wave = tid >> 6, lane = tid & 63;
    const int quad = lane >> 4, c = lane & 15;
    const int id  = blockIdx.x;
    const int h   = id & 7;
    const int qt  = (id >> 3) & 31;
    const int seg = id >> 8;
    const int q0  = qt * 128 + wave * 32;

    const unsigned short* qbaseA = Qp + ((((size_t)h << 12) + q0 + c) << 6) + quad * 8;
    const bf16x8 bQA0 = ldfrag(qbaseA);
    const bf16x8 bQA1 = ldfrag(qbaseA + 32);
    const bf16x8 bQB0 = ldfrag(qbaseA + 1024);
    const bf16x8 bQB1 = ldfrag(qbaseA + 1024 + 32);

    f32x4 oA[3], oB[3];
#pragma unroll
    for (int i = 0; i < 3; ++i) {
        oA[i] = (f32x4){0.f, 0.f, 0.f, 0.f};
        oB[i] = (f32x4){0.f, 0.f, 0.f, 0.f};
    }

    const int kt0 = seg * TILES;
    const unsigned short* kglob = Kp + (((size_t)h * Lkp + kt0 * 64) << 6);
    const unsigned short* vglob = Vt + ((size_t)h * 48) * Lkp + kt0 * 64;

    const int r0 = lane >> 3;
    const int g  = lane & 7;
    int ldsoff[4];
    const unsigned short* gptr0[4];
#pragma unroll
    for (int i = 0; i < 4; ++i) {
        int s = wave + 4 * i;
        if (s < 8) {
            int row = s * 8 + r0;
            ldsoff[i] = row * 64 + (g ^ (row & 7)) * 8;
            gptr0[i]  = kglob + (size_t)row * 64 + g * 8;
        } else if (s < 14) {
            int d = (s - 8) * 8 + r0;
            ldsoff[i] = d * 64 + (g ^ (d & 7)) * 8;
            gptr0[i]  = vglob + (size_t)d * Lkp + g * 8;
        } else {
            ldsoff[i] = 0; gptr0[i] = nullptr;
        }
    }
    const bool isK[4] = {(wave + 0) < 8, (wave + 4) < 8, (wave + 8) < 8, (wave + 12) < 8};
    const bool act[4] = {true, true, true, (wave + 12) < 14};

    {
        u16x8 st[4];
#pragma unroll
        for (int i = 0; i < 4; ++i)
            if (act[i]) st[i] = *(const u16x8*)(gptr0[i]);
#pragma unroll
        for (int i = 0; i < 4; ++i)
            if (act[i]) {
                unsigned short* lp = isK[i] ? &Kb[0][ldsoff[i]] : &Vb[0][ldsoff[i]];
                *(u16x8*)lp = st[i];
            }
    }
    __syncthreads();

#pragma unroll
    for (int t = 0; t < TILES; ++t) {
        const int b = t & 1;
        u16x8 st[4];
        if (t + 1 < TILES) {
            const int kb = (t + 1) * 64;
#pragma unroll
            for (int i = 0; i < 4; ++i)
                if (act[i]) {
                    const unsigned short* gp =
                        isK[i] ? (gptr0[i] + (size_t)kb * 64) : (gptr0[i] + kb);
                    st[i] = *(const u16x8*)gp;
                }
        }
        const unsigned short* Kl = &Kb[b][0];
        const unsigned short* Vl = &Vb[b][0];
        const int sw0 = (quad ^ (c & 7)) * 8;
        const int sw1 = ((quad + 4) ^ (c & 7)) * 8;
        const int abs_kb = kt0 * 64 + t * 64;
        // ---- per-blk pipeline: QK -> mask -> exp2 -> pack -> PV ----
#pragma unroll
        for (int blk = 0; blk < 4; ++blk) {
            const int row = (blk * 16 + c) * 64;
            bf16x8 k0 = ldfrag(Kl + row + sw0);
            bf16x8 k1 = ldfrag(Kl + row + sw1);
            f32x4 zA = {0.f, 0.f, 0.f, 0.f};
            zA = __builtin_amdgcn_mfma_f32_16x16x32_bf16(k0, bQA0, zA, 0, 0, 0);
            zA = __builtin_amdgcn_mfma_f32_16x16x32_bf16(k1, bQA1, zA, 0, 0, 0);
            f32x4 zB = {0.f, 0.f, 0.f, 0.f};
            zB = __builtin_amdgcn_mfma_f32_16x16x32_bf16(k0, bQB0, zB, 0, 0, 0);
            zB = __builtin_amdgcn_mfma_f32_16x16x32_bf16(k1, bQB1, zB, 0, 0, 0);
            if (MASK) {
#pragma unroll
                for (int r = 0; r < 4; ++r) {
                    bool inv = (abs_kb + blk * 16 + quad * 4 + r >= Lk);
                    zA[r] = inv ? -30000.f : zA[r];
                    zB[r] = inv ? -30000.f : zB[r];
                }
            }
            s16x4 PA = pk2frag(pk2bf(ex2(zA[0]), ex2(zA[1])),
                               pk2bf(ex2(zA[2]), ex2(zA[3])));
            s16x4 PB = pk2frag(pk2bf(ex2(zB[0]), ex2(zB[1])),
                               pk2bf(ex2(zB[2]), ex2(zB[3])));
#pragma unroll
            for (int db = 0; db < 3; ++db) {
                const int dim = db * 16 + c;
                const int off =
                    (((blk * 2 + (quad >> 1)) ^ (dim & 7)) * 8) + (quad & 1) * 4;
                s16x4 vf = *(const s16x4*)(Vl + dim * 64 + off);
                oA[db] = __builtin_amdgcn_mfma_f32_16x16x16bf16_1k(vf, PA, oA[db], 0, 0, 0);
                oB[db] = __builtin_amdgcn_mfma_f32_16x16x16bf16_1k(vf, PB, oB[db], 0, 0, 0);
            }
        }
        if (t + 1 < TILES) {
            const int nb = b ^ 1;
#pragma unroll
            for (int i = 0; i < 4; ++i)
                if (act[i]) {
                    unsigned short* lp = isK[i] ? &Kb[nb][ldsoff[i]] : &Vb[nb][ldsoff[i]];
                    *(u16x8*)lp = st[i];
                }
        }
        __syncthreads();
    }
    if (FINAL) {
        // Single-segment: finalize here. l for query (q0[+16]+c) lives in the
        // quad==2 lane (PV ones-row, dim 40 = oX[2][0]).
        float lA = __shfl(oA[2][0], 32 + c, 64);
        float lB = __shfl(oB[2][0], 32 + c, 64);
        float liA = fast_rcp(lA), liB = fast_rcp(lB);
        unsigned short* oaptr = Ofin + (size_t)(q0 + c) * CCH + h * DH;
        unsigned short* obptr = Ofin + (size_t)(q0 + 16 + c) * CCH + h * DH;
        *(uint2*)(oaptr + quad * 4) =
            make_uint2(pk2bf(oA[0][0] * liA, oA[0][1] * liA),
                       pk2bf(oA[0][2] * liA, oA[0][3] * liA));
        *(uint2*)(oaptr + 16 + quad * 4) =
            make_uint2(pk2bf(oA[1][0] * liA, oA[1][1] * liA),
                       pk2bf(oA[1][2] * liA, oA[1][3] * liA));
        if (quad < 2)
            *(uint2*)(oaptr + 32 + quad * 4) =
                make_uint2(pk2bf(oA[2][0] * liA, oA[2][1] * liA),
                           pk2bf(oA[2][2] * liA, oA[2][3] * liA));
        *(uint2*)(obptr + quad * 4) =
            make_uint2(pk2bf(oB[0][0] * liB, oB[0][1] * liB),
                       pk2bf(oB[0][2] * liB, oB[0][3] * liB));
        *(uint2*)(obptr + 16 + quad * 4) =
            make_uint2(pk2bf(oB[1][0] * liB, oB[1][1] * liB),
                       pk2bf(oB[1][2] * liB, oB[1][3] * liB));
        if (quad < 2)
            *(uint2*)(obptr + 32 + quad * 4) =
                make_uint2(pk2bf(oB[2][0] * liB, oB[2][1] * liB),
                           pk2bf(oB[2][2] * liB, oB[2][3] * liB));
        return;
    }
    // epilogue: dims 0..39 per query; l = PV row 40 = oX[2][0] at quad==2
    const size_t base = ((size_t)(seg * 8 + h)) << 12;
    float* obA = pO + (base + q0 + c) * 40;
    *(float4*)(obA + quad * 4)      = make_float4(oA[0][0], oA[0][1], oA[0][2], oA[0][3]);
    *(float4*)(obA + 16 + quad * 4) = make_float4(oA[1][0], oA[1][1], oA[1][2], oA[1][3]);
    if (quad < 2)
        *(float4*)(obA + 32 + quad * 4) = make_float4(oA[2][0], oA[2][1], oA[2][2], oA[2][3]);
    float* obB = pO + (base + q0 + 16 + c) * 40;
    *(float4*)(obB + quad * 4)      = make_float4(oB[0][0], oB[0][1], oB[0][2], oB[0][3]);
    *(float4*)(obB + 16 + quad * 4) = make_float4(oB[1][0], oB[1][1], oB[1][2], oB[1][3]);
    if (quad < 2)
        *(float4*)(obB + 32 + quad * 4) = make_float4(oB[2][0], oB[2][1], oB[2][2], oB[2][3]);
    if (quad == 2) {
        pL[base + q0 + c]      = oA[2][0];
        pL[base + q0 + 16 + c] = oB[2][0];
    }
}

// Combine partials (vectorized): float4 loads, packed bf16 stores.
__global__ __launch_bounds__(256) void attn_combine2(
    const float* __restrict__ pO, const float* __restrict__ pL,
    unsigned short* __restrict__ O, int S) {
    int idx = blockIdx.x * 256 + threadIdx.x;  // < 8*4096*10, grid 1280
    int h = idx / (HW * 10);
    int rem = idx - h * (HW * 10);
    int row = rem / 10, dg = rem - row * 10;
    float4 num = make_float4(0.f, 0.f, 0.f, 0.f);
    float den = 0.f;
    for (int s = 0; s < S; ++s) {
        size_t base = ((size_t)(s * 8 + h)) << 12;
        float4 p = *(const float4*)(pO + (base + row) * 40 + dg * 4);
        num.x += p.x; num.y += p.y; num.z += p.z; num.w += p.w;
        den += pL[base + row];
    }
    float inv = fast_rcp(den);
    unsigned short* ob = O + (size_t)row * CCH + h * DH + dg * 4;
    unsigned lo = pk2bf(num.x * inv, num.y * inv);
    unsigned hi = pk2bf(num.z * inv, num.w * inv);
    *(uint2*)ob = make_uint2(lo, hi);
}

// ---------------------------------------------------------------------------
extern "C" void kernel_launch(void* const* d_in, const int* in_sizes, int n_in,
                              void* d_out, int out_size, void* d_ws, size_t ws_size,
                              hipStream_t stream) {
    const float* x     = (const float*)d_in[0];
    const float* ctx   = (const float*)d_in[1];
    const float* gn_w  = (const float*)d_in[2];
    const float* gn_b  = (const float*)d_in[3];
    const float* w_in  = (const float*)d_in[4];
    const float* b_in  = (const float*)d_in[5];
    const float* ln1_w = (const float*)d_in[6];
    const float* ln1_b = (const float*)d_in[7];
    const float* wq1   = (const float*)d_in[8];
    const float* wk1   = (const float*)d_in[9];
    const float* wv1   = (const float*)d_in[10];
    const float* wo1   = (const float*)d_in[11];
    const float* bo1   = (const float*)d_in[12];
    const float* ln2_w = (const float*)d_in[13];
    const float* ln2_b = (const float*)d_in[14];
    const float* wq2   = (const float*)d_in[15];
    const float* wk2   = (const float*)d_in[16];
    const float* wv2   = (const float*)d_in[17];
    const float* wo2   = (const float*)d_in[18];
    const float* bo2   = (const float*)d_in[19];
    const float* ln3_w = (const float*)d_in[20];
    const float* ln3_b = (const float*)d_in[21];
    const float* wff1  = (const float*)d_in[22];
    const float* bff1  = (const float*)d_in[23];
    const float* wff2  = (const float*)d_in[24];
    const float* bff2  = (const float*)d_in[25];
    const float* w_out = (const float*)d_in[26];
    const float* b_out = (const float*)d_in[27];
    float* out = (float*)d_out;

    const int NT = HW * CCH;  // 1,310,720
    // 8 segments if the workspace allows, else 4.
    const size_t u16_cnt = (size_t)NT * 3 + (size_t)HW * FFI +
                           (size_t)8 * 4096 * 64 * 2 + (size_t)8 * 48 * 4096 +
                           8 * 128 * 64 + 8 * 48 * 128 + WT_TOTAL + 128 * 768;
    const size_t need8 = (size_t)4 * (NT + 8 * NT + 8 * 32768 + 512) +
                         2 * u16_cnt + 4096;
    const int SEGS = (ws_size >= need8) ? 8 : 4;

    float* ws = (float*)d_ws;
    float* t_   = ws;
    float* pO   = t_ + NT;
    float* pL   = pO + (size_t)SEGS * NT;
    float2* gnp = (float2*)(pL + (size_t)SEGS * 8 * 4096);
    unsigned short* u = (unsigned short*)(gnp + 256);
    unsigned short* a_bf = u;                  u += NT;
    unsigned short* o_bf = u;                  u += NT;
    unsigned short* t_bf = u;                  u += NT;
    unsigned short* g_bf = u;                  u += HW * FFI;
    unsigned short* Qp   = u;                  u += 8 * 4096 * 64;
    unsigned short* Kp   = u;                  u += 8 * 4096 * 64;
    unsigned short* Vt   = u;                  u += 8 * 48 * 4096;  // after Kp!
    unsigned short* Kc   = u;                  u += 8 * 128 * 64;
    unsigned short* Vc   = u;                  u += 8 * 48 * 128;
    unsigned short* Wt   = u;                  u += WT_TOTAL;
    unsigned short* ctx_bf = u;                u += 128 * 768;

    const unsigned short* w_inT  = Wt;
    const unsigned short* wo1T   = Wt + 409600;
    const unsigned short* wq2T   = Wt + 512000;
    const unsigned short* wo2T   = Wt + 614400;
    const unsigned short* w_outT = Wt + 716800;
    const unsigned short* wff1T  = Wt + 819200;
    const unsigned short* wff2T  = Wt + 1638400;
    const unsigned short* wk2T   = Wt + 2048000;  // wv2T contiguous (N=640)
    const unsigned short* wk1T   = Wt + 204800;   // wv1T contiguous (N=640)
    const unsigned short* Wq1bf  = Wt + WQ1BF_OFF;
    unsigned short*       W2     = Wt + W2_OFF;   // [wq1T | WqkT | WqvT] 960x320

    const float qscale = 0.15811388300841897f * 1.4426950408889634f;  // 40^-.5 * log2e

    // 0) mega-prep: weight transposes + wq1 copies + pack_ctx + gn_stats
    megaprep<<<1310, 256, 0, stream>>>(w_in, wq1, wk1, wv1, wo1, wq2, wo2, w_out,
                                       wff1, wff2, wk2, wv2, Wt, ctx, ctx_bf,
                                       x, gnp);
    // 0b+1) prep2: fused K/V weights (mode 10) + GroupNorm apply -> a_bf
    prep2<<<420, 256, 0, stream>>>(Wq1bf, wk1T, W2 + (size_t)320 * 320,
                                   x, gnp, gn_w, gn_b, a_bf);
    // 2) proj_in: t = a @ w_in + b_in (fp32)
    gemm4<2, 320><<<dim3(5, 128), 256, 0, stream>>>(a_bf, w_inT, b_in, nullptr, t_, nullptr, CCH, 0, 1.f);
    // 3) ln1 -> a_bf
    ln_kernel<<<1024, 256, 0, stream>>>(t_, ln1_w, ln1_b, a_bf);
    // 4) fused QKV: [q|k|v] = a_bf @ W2^T -> Qp/Kp/Vt packed (pads+ones)
    gemm4<2, 320><<<dim3(15, 128), 256, 0, stream>>>(a_bf, W2, nullptr, nullptr, Qp, Kp, 960, 11, qscale);
    // 5) self-attention: 128 queries/block, SEGS segments
    if (SEGS == 8)
        attn8<8, false, false><<<2048, 256, 0, stream>>>(Qp, Kp, Vt, pO, pL, nullptr, HW, HW);
    else
        attn8<16, false, false><<<1024, 256, 0, stream>>>(Qp, Kp, Vt, pO, pL, nullptr, HW, HW);
    attn_combine2<<<1280, 256, 0, stream>>>(pO, pL, o_bf, SEGS);
    // 6) t += o @ wo1 + bo1
    gemm4<2, 320><<<dim3(5, 128), 256, 0, stream>>>(o_bf, wo1T, bo1, t_, t_, nullptr, CCH, 0, 1.f);
    // 7) ln2 -> a_bf
    ln_kernel<<<1024, 256, 0, stream>>>(t_, ln2_w, ln2_b, a_bf);
    // 8) merged: cross q -> Qp (mode 2) + ctx K/V -> Kc/Vc (mode 8)
    cross_merged<<<680, 256, 0, stream>>>(a_bf, wq2T, Qp, qscale,
                                          ctx_bf, wk2T, Kc, Vc);
    // 9) cross-attention (Lk=77, masked, single-seg -> finalize in-kernel)
    attn8<2, true, true><<<256, 256, 0, stream>>>(Qp, Kc, Vc, nullptr, nullptr, o_bf, 77, 128);
    // 10) t += o @ wo2 + bo2
    gemm4<2, 320><<<dim3(5, 128), 256, 0, stream>>>(o_bf, wo2T, bo2, t_, t_, nullptr, CCH, 0, 1.f);
    // 11) ln3 -> a_bf
    ln_kernel<<<1024, 256, 0, stream>>>(t_, ln3_w, ln3_b, a_bf);
    // 12+13) FF1 with fused GEGLU -> g_bf
    gemm4<2, 320><<<dim3(40, 128), 256, 0, stream>>>(a_bf, wff1T, bff1, nullptr, g_bf, nullptr, 2 * FFI, 5, 1.f);
    // 14) t_bf = bf16(t + g @ wff2 + bff2)
    gemm4<2, 1280><<<dim3(5, 128), 256, 0, stream>>>(g_bf, wff2T, bff2, t_, t_bf, nullptr, CCH, 4, 1.f);
    // 15+16) out = (t_bf @ w_out + b_out)^T + x  (final fused, mode 9)
    gemm4<2, 320><<<dim3(5, 128), 256, 0, stream>>>(t_bf, w_outT, b_out, x, out, nullptr, CCH, 9, 1.f);
}